// Round 18
// baseline (1562.712 us; speedup 1.0000x reference)
//
#include <hip/hip_runtime.h>

typedef unsigned short u16;
typedef __attribute__((ext_vector_type(8))) short bf16x8;
typedef __attribute__((ext_vector_type(4))) short bf16x4;
typedef __attribute__((ext_vector_type(4))) float f32x4;

#define MFMA16(a, b, c) __builtin_amdgcn_mfma_f32_16x16x32_bf16((a), (b), (c), 0, 0, 0)

// workspace layout (u16 element offsets)
#define OFF_U8   0           // 8 shifted u_pad copies: [8][1024][584]
#define U8_CPY   598016      // 1024*584
#define OFF_KS0  4784128
#define OFF_W0   5046272
#define OFF_W1   5177344
#define OFF_W2   5308416
#define OFF_CRT  5373952
#define OFF_P    5390336     // 65 x 65536 (A^t, bf16)
#define OFF_H1   9650176     // chunk H1: 129*1024*512 u16
#define OS_OFF   134479872   // 513*1024*256

__device__ __forceinline__ u16 f2bf(float f) {
  union { float f; unsigned int i; } v; v.f = f;
  return (u16)((v.i + 0x7fffu + ((v.i >> 16) & 1u)) >> 16);
}
__device__ __forceinline__ float bf2f(u16 u) {
  union { unsigned int i; float f; } v; v.i = ((unsigned int)u) << 16;
  return v.f;
}
__device__ __forceinline__ float fast_tanh(float x) {
  float e = __expf(2.0f * x);
  return 1.0f - __fdividef(2.0f, e + 1.0f);
}

// ---------------- prep: u8 shifted copies + bf16 conversions + P0/P1 ----------------
__global__ void k_prep(const float* __restrict__ KS_ALL, const float* __restrict__ next_vf,
                       const float* __restrict__ A_w, const float* __restrict__ W0,
                       const float* __restrict__ W1, const float* __restrict__ W2,
                       u16* __restrict__ ws) {
  int idx = blockIdx.x * 256 + threadIdx.x;
  if (idx < 4784128) {  // u8[p][b][c] = u_pad[b][c+p]
    int p = idx / U8_CPY;
    int rem = idx - p * U8_CPY;
    int b = rem / 584;
    int c = rem - b * 584;
    int col = c + p;
    ws[OFF_U8 + idx] = (col >= 64 && col < 576) ? f2bf(next_vf[b * 512 + col - 64]) : (u16)0;
    return;
  }
  idx -= 4784128;
  if (idx < 262144) { ws[OFF_KS0 + idx] = f2bf(KS_ALL[idx]); return; }
  idx -= 262144;
  if (idx < 131072) { ws[OFF_W0 + idx] = f2bf(W0[idx]); return; }
  idx -= 131072;
  if (idx < 131072) { ws[OFF_W1 + idx] = f2bf(W1[idx]); return; }
  idx -= 131072;
  if (idx < 65536)  { ws[OFF_W2 + idx] = f2bf(W2[idx]); return; }
  idx -= 65536;
  if (idx < 65536) { // P0 = I, P1 = A
    int r = idx >> 8, c = idx & 255;
    ws[OFF_P + idx] = (r == c) ? (u16)0x3F80 : (u16)0;
    ws[OFF_P + 65536 + idx] = f2bf(A_w[idx]);
  }
}

// ---------------- power doubling ----------------
__global__ __launch_bounds__(512) void k_pow(u16* __restrict__ ws, int s) {
  const u16* P = ws + OFF_P;
  int j = blockIdx.y + 1;
  int mh = blockIdx.x;
  int lane = threadIdx.x & 63, w = threadIdx.x >> 6;
  int wm = w >> 2, wn = w & 3;
  int lg = lane >> 4, ll = lane & 15;
  const u16* Am = P + s * 65536;
  const u16* Bm = P + j * 65536;
  f32x4 acc[4][4];
  f32x4 z = {0.f, 0.f, 0.f, 0.f};
#pragma unroll
  for (int mi = 0; mi < 4; ++mi)
#pragma unroll
    for (int ni = 0; ni < 4; ++ni) acc[mi][ni] = z;
#pragma unroll
  for (int ks = 0; ks < 8; ++ks) {
    bf16x8 a[4], b[4];
    int kk = ks * 32 + lg * 8;
#pragma unroll
    for (int mi = 0; mi < 4; ++mi) {
      int row = mh * 128 + wm * 64 + mi * 16 + ll;
      a[mi] = *(const bf16x8*)(Am + row * 256 + kk);
    }
#pragma unroll
    for (int ni = 0; ni < 4; ++ni) {
      int col = wn * 64 + ni * 16 + ll;
#pragma unroll
      for (int e = 0; e < 8; ++e) b[ni][e] = (short)Bm[(kk + e) * 256 + col];
    }
#pragma unroll
    for (int mi = 0; mi < 4; ++mi)
#pragma unroll
      for (int ni = 0; ni < 4; ++ni) acc[mi][ni] = MFMA16(a[mi], b[ni], acc[mi][ni]);
  }
  u16* Pd = ws + OFF_P + (s + j) * 65536;
#pragma unroll
  for (int mi = 0; mi < 4; ++mi)
#pragma unroll
    for (int ni = 0; ni < 4; ++ni)
#pragma unroll
      for (int r = 0; r < 4; ++r) {
        int row = mh * 128 + wm * 64 + mi * 16 + lg * 4 + r;
        int col = wn * 64 + ni * 16 + ll;
        Pd[row * 256 + col] = f2bf(acc[mi][ni][r]);
      }
}

// ---------------- CrevT[n][s] = c_{63-s}[n] ----------------
__global__ void k_crevt(const float* __restrict__ B_w, u16* __restrict__ ws) {
  int s = blockIdx.x;
  int n = threadIdx.x;
  const u16* Pr = ws + OFF_P + (63 - s) * 65536 + n * 256;
  float acc = 0.f;
  for (int k = 0; k < 256; ++k) acc += bf2f(Pr[k]) * B_w[k];
  ws[OFF_CRT + n * 64 + s] = f2bf(acc);
}

// ---- A+B: KS gen + coalesced NT KS store + L1 (X never leaves the block) ----
// (R17, proven: absmax 0.047, ~170us/chunk)
__global__ __launch_bounds__(512) void k_ksl1(const u16* __restrict__ ws,
                                              const float* __restrict__ b0,
                                              u16* __restrict__ h1,
                                              float* __restrict__ out, int t0) {
  __shared__ __align__(16) u16 Xb[16896];             // [64][256] bf16 swz
  __shared__ __align__(16) unsigned char Hraw[33792]; // f32 bounce [32][260] / u16 Hb [64][264]
  __shared__ float pb0s[512];
  float* Hf = (float*)Hraw;
  u16* Hb = (u16*)Hraw;
  const int by = blockIdx.y;
  const int t  = t0 + by;
  const int R0 = blockIdx.x * 64;
  const int tid = threadIdx.x;
  const int lane = tid & 63, w = tid >> 6;
  const int lg = lane >> 4, ll = lane & 15;
  f32x4 z = {0.f, 0.f, 0.f, 0.f};

  pb0s[tid] = b0[tid];

  // ---- phase 1: KS rows R0..R0+63; wave w cols w*32..+31 ----
  f32x4 acc[4][2];
#pragma unroll
  for (int mi = 0; mi < 4; ++mi)
#pragma unroll
    for (int ni = 0; ni < 2; ++ni) acc[mi][ni] = z;
  {
    const u16* CrevT = ws + OFF_CRT;
    const u16* u8b = ws + OFF_U8 + (size_t)(t & 7) * U8_CPY + (t & ~7);
#pragma unroll
    for (int ksu = 0; ksu < 2; ++ksu) {
      bf16x8 au[4];
#pragma unroll
      for (int mi = 0; mi < 4; ++mi)
        au[mi] = *(const bf16x8*)(u8b + (R0 + mi * 16 + ll) * 584 + ksu * 32 + lg * 8);
#pragma unroll
      for (int ni = 0; ni < 2; ++ni) {
        int n = w * 32 + ni * 16 + ll;
        bf16x8 bfr = *(const bf16x8*)(CrevT + n * 64 + ksu * 32 + lg * 8);
#pragma unroll
        for (int mi = 0; mi < 4; ++mi) acc[mi][ni] = MFMA16(au[mi], bfr, acc[mi][ni]);
      }
    }
    if (t < 64) {
      const u16* Pt = ws + OFF_P + t * 65536;
      const u16* ks0b = ws + OFF_KS0;
#pragma unroll
      for (int ks = 0; ks < 8; ++ks) {
        bf16x8 a[4], b[2];
#pragma unroll
        for (int mi = 0; mi < 4; ++mi)
          a[mi] = *(const bf16x8*)(ks0b + (R0 + mi * 16 + ll) * 256 + ks * 32 + lg * 8);
#pragma unroll
        for (int ni = 0; ni < 2; ++ni)
          b[ni] = *(const bf16x8*)(Pt + (w * 32 + ni * 16 + ll) * 256 + ks * 32 + lg * 8);
#pragma unroll
        for (int mi = 0; mi < 4; ++mi)
#pragma unroll
          for (int ni = 0; ni < 2; ++ni) acc[mi][ni] = MFMA16(a[mi], b[ni], acc[mi][ni]);
      }
    }
  }

  // ---- build Xb (bf16 swz) straight from registers ----
#pragma unroll
  for (int mi = 0; mi < 4; ++mi)
#pragma unroll
    for (int ni = 0; ni < 2; ++ni)
#pragma unroll
      for (int r = 0; r < 4; ++r) {
        int rl = mi * 16 + lg * 4 + r;
        int col = w * 32 + ni * 16 + ll;
        int byt = ((rl << 9) + (col << 1)) ^ ((rl & 7) << 4);
        Xb[byt >> 1] = f2bf(acc[mi][ni][r]);
      }

  // ---- KS f32 store via bounce, 2 passes of 32 rows ----
#pragma unroll 1
  for (int p = 0; p < 2; ++p) {
#pragma unroll
    for (int mi2 = 0; mi2 < 2; ++mi2) {
      int mi = p * 2 + mi2;
#pragma unroll
      for (int ni = 0; ni < 2; ++ni)
#pragma unroll
        for (int r = 0; r < 4; ++r)
          Hf[(mi2 * 16 + lg * 4 + r) * 260 + w * 32 + ni * 16 + ll] = acc[mi][ni][r];
    }
    __syncthreads();
    float* ob = out + (size_t)t * 262144 + (size_t)(R0 + p * 32) * 256;
#pragma unroll
    for (int it = 0; it < 4; ++it) {
      int idx = it * 512 + tid;
      int row = idx >> 6, c4 = idx & 63;
      f32x4 v = *(const f32x4*)(Hf + row * 260 + c4 * 4);
      __builtin_nontemporal_store(v, (f32x4*)(ob + row * 256 + c4 * 4));
    }
    __syncthreads();
  }

  // ---- L1: H1 = tanh(X @ W0^T + b0); two 256-col halves; NT store to h1 ----
  const u16* W0b = ws + OFF_W0;
#pragma unroll 1
  for (int nh = 0; nh < 2; ++nh) {
    f32x4 acc2[4][2];
#pragma unroll
    for (int mi = 0; mi < 4; ++mi)
#pragma unroll
      for (int ni = 0; ni < 2; ++ni) acc2[mi][ni] = z;
#pragma unroll
    for (int ks = 0; ks < 8; ++ks) {
      bf16x8 b[2];
#pragma unroll
      for (int ni = 0; ni < 2; ++ni) {
        int n = nh * 256 + w * 32 + ni * 16 + ll;
        b[ni] = *(const bf16x8*)(W0b + n * 256 + ks * 32 + lg * 8);
      }
#pragma unroll
      for (int mi = 0; mi < 4; ++mi) {
        int rl = mi * 16 + ll;
        int byt = ((rl << 9) + ks * 64 + (lg << 4)) ^ ((rl & 7) << 4);
        bf16x8 a = *(const bf16x8*)(Xb + (byt >> 1));
#pragma unroll
        for (int ni = 0; ni < 2; ++ni) acc2[mi][ni] = MFMA16(a, b[ni], acc2[mi][ni]);
      }
    }
#pragma unroll
    for (int mi = 0; mi < 4; ++mi)
#pragma unroll
      for (int ni = 0; ni < 2; ++ni)
#pragma unroll
        for (int r = 0; r < 4; ++r) {
          int rl = mi * 16 + lg * 4 + r;
          int col = w * 32 + ni * 16 + ll;
          Hb[rl * 264 + col] = f2bf(fast_tanh(acc2[mi][ni][r] + pb0s[nh * 256 + col]));
        }
    __syncthreads();
    u16* hd = h1 + ((size_t)(by * 1024 + R0)) * 512 + nh * 256;
#pragma unroll
    for (int it = 0; it < 4; ++it) {
      int idx = it * 512 + tid;
      int row = idx >> 5, cq = idx & 31;
      bf16x8 v = *(const bf16x8*)(Hb + row * 264 + cq * 8);
      __builtin_nontemporal_store(v, (bf16x8*)(hd + row * 512 + cq * 8));
    }
    __syncthreads();
  }
}

// ---- C: OS = elu(LN(X + tanh(H1 @ W1^T + b1)) @ W2^T + b2) @ W3^T + b3 ----
// T14 async-stage: both H1 halves' NT loads issued at entry; half-1 ds_writes land
// in Rb (aliased stage buffer, no extra LDS); X NT loads issued before the GEMM-1
// barrier so they complete under the MFMA phase.
__global__ __launch_bounds__(512) void k_l23(const u16* __restrict__ ws,
                                             const float* __restrict__ outf,
                                             const float* __restrict__ b1,
                                             const float* __restrict__ lng,
                                             const float* __restrict__ lnb,
                                             const float* __restrict__ b2,
                                             const float* __restrict__ W3,
                                             const float* __restrict__ b3,
                                             const u16* __restrict__ h1,
                                             float* __restrict__ out, int t0) {
  __shared__ __align__(16) u16 Hs[16896];  // H1 half-0 stage swz / elu out [64][264]
  __shared__ __align__(16) u16 Rb[16896];  // H1 half-1 stage swz, then resid/LN [64][264]
  __shared__ float par[1796];
  __shared__ float osb[208];
  float* pb1 = par;          // 256
  float* pg  = par + 256;    // 256
  float* pbt = par + 512;    // 256
  float* pb2 = par + 768;    // 256
  float* pW3 = par + 1024;   // 768
  float* pb3 = par + 1792;   // 4
  const int by = blockIdx.y;
  const int t  = t0 + by;
  const int R0 = blockIdx.x * 64;
  const int tid = threadIdx.x;
  const int lane = tid & 63, w = tid >> 6;
  const int lg = lane >> 4, ll = lane & 15;
  f32x4 z = {0.f, 0.f, 0.f, 0.f};

  if (tid < 256) { pb1[tid] = b1[tid]; pg[tid] = lng[tid]; pbt[tid] = lnb[tid]; pb2[tid] = b2[tid]; }
  if (tid < 512) pW3[tid] = W3[tid];
  if (tid < 256) pW3[512 + tid] = W3[512 + tid];
  if (tid < 4) pb3[tid] = (tid < 3) ? b3[tid] : 0.f;

  const u16* W1b = ws + OFF_W1;
  const u16* h1b = h1 + ((size_t)(by * 1024 + R0)) * 512;
  const float* xs = outf + (size_t)t * 262144 + (size_t)R0 * 256;

  // prefetch BOTH H1 halves (NT); half-1 stays in regs until after GEMM-0
  bf16x8 v0[4], v1[4];
#pragma unroll
  for (int it = 0; it < 4; ++it) {
    int idx = it * 512 + tid;
    int row = idx >> 5, cq = idx & 31;
    v0[it] = __builtin_nontemporal_load((const bf16x8*)(h1b + row * 512 + cq * 8));
    v1[it] = __builtin_nontemporal_load((const bf16x8*)(h1b + row * 512 + 256 + cq * 8));
  }
#pragma unroll
  for (int it = 0; it < 4; ++it) {
    int idx = it * 512 + tid;
    int row = idx >> 5, cq = idx & 31;
    int byt = ((row << 9) + (cq << 4)) ^ ((row & 7) << 4);
    *(bf16x8*)(Hs + (byt >> 1)) = v0[it];
  }
  __syncthreads();

  f32x4 accL2[4][2];
#pragma unroll
  for (int mi = 0; mi < 4; ++mi)
#pragma unroll
    for (int ni = 0; ni < 2; ++ni) accL2[mi][ni] = z;

  // GEMM half 0 (reads Hs)
#pragma unroll
  for (int ks = 0; ks < 8; ++ks) {
    bf16x8 b[2];
#pragma unroll
    for (int ni = 0; ni < 2; ++ni) {
      int n = w * 32 + ni * 16 + ll;
      b[ni] = *(const bf16x8*)(W1b + n * 512 + ks * 32 + lg * 8);
    }
#pragma unroll
    for (int mi = 0; mi < 4; ++mi) {
      int rl = mi * 16 + ll;
      int byt = ((rl << 9) + ks * 64 + (lg << 4)) ^ ((rl & 7) << 4);
      bf16x8 a = *(const bf16x8*)(Hs + (byt >> 1));
#pragma unroll
      for (int ni = 0; ni < 2; ++ni) accL2[mi][ni] = MFMA16(a, b[ni], accL2[mi][ni]);
    }
  }

  // write half-1 stage into Rb (different buffer than GEMM-0's reads: no barrier needed)
#pragma unroll
  for (int it = 0; it < 4; ++it) {
    int idx = it * 512 + tid;
    int row = idx >> 5, cq = idx & 31;
    int byt = ((row << 9) + (cq << 4)) ^ ((row & 7) << 4);
    *(bf16x8*)((u16*)Rb + (byt >> 1)) = v1[it];
  }
  // issue X loads (fragment mapping) — complete under GEMM-1
  float xv[4][2][4];
#pragma unroll
  for (int mi = 0; mi < 4; ++mi)
#pragma unroll
    for (int ni = 0; ni < 2; ++ni)
#pragma unroll
      for (int r = 0; r < 4; ++r) {
        int rl = mi * 16 + lg * 4 + r;
        int col = w * 32 + ni * 16 + ll;
        xv[mi][ni][r] = __builtin_nontemporal_load(xs + rl * 256 + col);
      }
  __syncthreads();

  // GEMM half 1 (reads Rb-as-stage)
#pragma unroll
  for (int ks = 0; ks < 8; ++ks) {
    bf16x8 b[2];
#pragma unroll
    for (int ni = 0; ni < 2; ++ni) {
      int n = w * 32 + ni * 16 + ll;
      b[ni] = *(const bf16x8*)(W1b + n * 512 + 256 + ks * 32 + lg * 8);
    }
#pragma unroll
    for (int mi = 0; mi < 4; ++mi) {
      int rl = mi * 16 + ll;
      int byt = ((rl << 9) + ks * 64 + (lg << 4)) ^ ((rl & 7) << 4);
      bf16x8 a = *(const bf16x8*)((const u16*)Rb + (byt >> 1));
#pragma unroll
      for (int ni = 0; ni < 2; ++ni) accL2[mi][ni] = MFMA16(a, b[ni], accL2[mi][ni]);
    }
  }
  __syncthreads();  // all GEMM-1 reads of Rb done before resid overwrites it

  // residual: Rb = f2bf(X + tanh(accL2 + b1))
#pragma unroll
  for (int mi = 0; mi < 4; ++mi)
#pragma unroll
    for (int ni = 0; ni < 2; ++ni)
#pragma unroll
      for (int r = 0; r < 4; ++r) {
        int rl = mi * 16 + lg * 4 + r;
        int col = w * 32 + ni * 16 + ll;
        float v = xv[mi][ni][r] + fast_tanh(accL2[mi][ni][r] + pb1[col]);
        Rb[rl * 264 + col] = f2bf(v);
      }
  __syncthreads();

  // LayerNorm per row in place; 8 lanes/row
  {
    int row = tid >> 3, jq = tid & 7;
    u16* hr = Rb + row * 264 + jq * 32;
    bf16x8 chv[4];
#pragma unroll
    for (int q = 0; q < 4; ++q) chv[q] = *(const bf16x8*)(hr + q * 8);
    float s = 0.f, ss = 0.f;
#pragma unroll
    for (int q = 0; q < 4; ++q)
#pragma unroll
      for (int e = 0; e < 8; ++e) { float v = bf2f((u16)chv[q][e]); s += v; ss += v * v; }
    s += __shfl_xor(s, 1);  s += __shfl_xor(s, 2);  s += __shfl_xor(s, 4);
    ss += __shfl_xor(ss, 1); ss += __shfl_xor(ss, 2); ss += __shfl_xor(ss, 4);
    float mu = s * 0.00390625f;
    float var = ss * 0.00390625f - mu * mu;
    float rstd = rsqrtf(var + 1e-5f);
#pragma unroll
    for (int q = 0; q < 4; ++q) {
      bf16x8 o;
#pragma unroll
      for (int e = 0; e < 8; ++e) {
        int col = jq * 32 + q * 8 + e;
        float v = (bf2f((u16)chv[q][e]) - mu) * rstd * pg[col] + pbt[col];
        o[e] = (short)f2bf(v);
      }
      *(bf16x8*)(hr + q * 8) = o;
    }
  }
  __syncthreads();

  // L3: elu(s2n @ W2^T + b2) -> Hs (reused) [64][264]
  {
    const u16* W2b = ws + OFF_W2;
    f32x4 a3[4][2];
#pragma unroll
    for (int mi = 0; mi < 4; ++mi)
#pragma unroll
      for (int ni = 0; ni < 2; ++ni) a3[mi][ni] = z;
#pragma unroll
    for (int ks = 0; ks < 8; ++ks) {
      bf16x8 b[2];
#pragma unroll
      for (int ni = 0; ni < 2; ++ni) {
        int n = w * 32 + ni * 16 + ll;
        b[ni] = *(const bf16x8*)(W2b + n * 256 + ks * 32 + lg * 8);
      }
#pragma unroll
      for (int mi = 0; mi < 4; ++mi) {
        int rl = mi * 16 + ll;
        bf16x8 a = *(const bf16x8*)(Rb + rl * 264 + ks * 32 + lg * 8);
#pragma unroll
        for (int ni = 0; ni < 2; ++ni) a3[mi][ni] = MFMA16(a, b[ni], a3[mi][ni]);
      }
    }
#pragma unroll
    for (int mi = 0; mi < 4; ++mi)
#pragma unroll
      for (int ni = 0; ni < 2; ++ni)
#pragma unroll
        for (int r = 0; r < 4; ++r) {
          int rl = mi * 16 + lg * 4 + r;
          int col = w * 32 + ni * 16 + ll;
          float v = a3[mi][ni][r] + pb2[col];
          v = v > 0.f ? v : (__expf(v) - 1.f);
          Hs[rl * 264 + col] = f2bf(v);
        }
  }
  __syncthreads();

  // OS reduce into LDS, then coalesced store
  {
    int row = tid >> 3, jq = tid & 7;
    const u16* xr = Hs + row * 264 + jq * 32;
    float d0 = 0.f, d1 = 0.f, d2 = 0.f;
#pragma unroll
    for (int q = 0; q < 4; ++q) {
      bf16x8 c = *(const bf16x8*)(xr + q * 8);
#pragma unroll
      for (int e = 0; e < 8; ++e) {
        float v = bf2f((u16)c[e]);
        int col = jq * 32 + q * 8 + e;
        d0 += v * pW3[col]; d1 += v * pW3[256 + col]; d2 += v * pW3[512 + col];
      }
    }
    d0 += __shfl_xor(d0, 1); d0 += __shfl_xor(d0, 2); d0 += __shfl_xor(d0, 4);
    d1 += __shfl_xor(d1, 1); d1 += __shfl_xor(d1, 2); d1 += __shfl_xor(d1, 4);
    d2 += __shfl_xor(d2, 1); d2 += __shfl_xor(d2, 2); d2 += __shfl_xor(d2, 4);
    if (jq == 0) {
      osb[row * 3]     = d0 + pb3[0];
      osb[row * 3 + 1] = d1 + pb3[1];
      osb[row * 3 + 2] = d2 + pb3[2];
    }
  }
  __syncthreads();
  if (tid < 48) {
    f32x4 v = *(const f32x4*)(osb + tid * 4);
    __builtin_nontemporal_store(v, (f32x4*)(out + OS_OFF + (size_t)t * 3072 + (size_t)R0 * 3 + tid * 4));
  }
}

extern "C" void kernel_launch(void* const* d_in, const int* in_sizes, int n_in,
                              void* d_out, int out_size, void* d_ws, size_t ws_size,
                              hipStream_t stream) {
  const float* KS_ALL  = (const float*)d_in[0];
  const float* next_vf = (const float*)d_in[1];
  const float* A_w     = (const float*)d_in[2];
  const float* B_w     = (const float*)d_in[3];
  const float* W0      = (const float*)d_in[4];
  const float* b0      = (const float*)d_in[5];
  const float* W1      = (const float*)d_in[6];
  const float* b1      = (const float*)d_in[7];
  const float* lng     = (const float*)d_in[8];
  const float* lnb     = (const float*)d_in[9];
  const float* W2      = (const float*)d_in[10];
  const float* b2      = (const float*)d_in[11];
  const float* W3      = (const float*)d_in[12];
  const float* b3      = (const float*)d_in[13];
  u16* ws = (u16*)d_ws;
  float* out = (float*)d_out;

  k_prep<<<21248, 256, 0, stream>>>(KS_ALL, next_vf, A_w, W0, W1, W2, ws);
  for (int s = 1; s <= 32; s <<= 1)
    k_pow<<<dim3(2, s), 512, 0, stream>>>(ws, s);
  k_crevt<<<64, 256, 0, stream>>>(B_w, ws);

  u16* h1 = ws + OFF_H1;
  const int t0s[4] = {0, 129, 257, 385};
  const int nts[4] = {129, 128, 128, 128};
  for (int c = 0; c < 4; ++c) {
    k_ksl1<<<dim3(16, nts[c]), 512, 0, stream>>>(ws, b0, h1, out, t0s[c]);
    k_l23<<<dim3(16, nts[c]), 512, 0, stream>>>(ws, out, b1, lng, lnb, b2, W3, b3, h1, out, t0s[c]);
  }
}

// Round 19
// 1369.185 us; speedup vs baseline: 1.1413x; 1.1413x over previous
//
#include <hip/hip_runtime.h>

typedef unsigned short u16;
typedef __attribute__((ext_vector_type(8))) short bf16x8;
typedef __attribute__((ext_vector_type(4))) short bf16x4;
typedef __attribute__((ext_vector_type(4))) float f32x4;

#define MFMA16(a, b, c) __builtin_amdgcn_mfma_f32_16x16x32_bf16((a), (b), (c), 0, 0, 0)

// workspace layout (u16 element offsets)
#define OFF_U8   0           // 8 shifted u_pad copies: [8][1024][584]
#define U8_CPY   598016      // 1024*584
#define OFF_KS0  4784128
#define OFF_W0   5046272
#define OFF_W1   5177344
#define OFF_W2   5308416
#define OFF_CRT  5373952
#define OFF_P    5390336     // 65 x 65536 (A^t, bf16)
#define OFF_H1   9650176     // chunk H1: 129*1024*512 u16
#define OS_OFF   134479872   // 513*1024*256

__device__ __forceinline__ u16 f2bf(float f) {
  union { float f; unsigned int i; } v; v.f = f;
  return (u16)((v.i + 0x7fffu + ((v.i >> 16) & 1u)) >> 16);
}
__device__ __forceinline__ float bf2f(u16 u) {
  union { unsigned int i; float f; } v; v.i = ((unsigned int)u) << 16;
  return v.f;
}
__device__ __forceinline__ float fast_tanh(float x) {
  float e = __expf(2.0f * x);
  return 1.0f - __fdividef(2.0f, e + 1.0f);
}

// ---------------- prep: u8 shifted copies + bf16 conversions + P0/P1 ----------------
__global__ void k_prep(const float* __restrict__ KS_ALL, const float* __restrict__ next_vf,
                       const float* __restrict__ A_w, const float* __restrict__ W0,
                       const float* __restrict__ W1, const float* __restrict__ W2,
                       u16* __restrict__ ws) {
  int idx = blockIdx.x * 256 + threadIdx.x;
  if (idx < 4784128) {  // u8[p][b][c] = u_pad[b][c+p]
    int p = idx / U8_CPY;
    int rem = idx - p * U8_CPY;
    int b = rem / 584;
    int c = rem - b * 584;
    int col = c + p;
    ws[OFF_U8 + idx] = (col >= 64 && col < 576) ? f2bf(next_vf[b * 512 + col - 64]) : (u16)0;
    return;
  }
  idx -= 4784128;
  if (idx < 262144) { ws[OFF_KS0 + idx] = f2bf(KS_ALL[idx]); return; }
  idx -= 262144;
  if (idx < 131072) { ws[OFF_W0 + idx] = f2bf(W0[idx]); return; }
  idx -= 131072;
  if (idx < 131072) { ws[OFF_W1 + idx] = f2bf(W1[idx]); return; }
  idx -= 131072;
  if (idx < 65536)  { ws[OFF_W2 + idx] = f2bf(W2[idx]); return; }
  idx -= 65536;
  if (idx < 65536) { // P0 = I, P1 = A
    int r = idx >> 8, c = idx & 255;
    ws[OFF_P + idx] = (r == c) ? (u16)0x3F80 : (u16)0;
    ws[OFF_P + 65536 + idx] = f2bf(A_w[idx]);
  }
}

// ---------------- power doubling ----------------
__global__ __launch_bounds__(512) void k_pow(u16* __restrict__ ws, int s) {
  const u16* P = ws + OFF_P;
  int j = blockIdx.y + 1;
  int mh = blockIdx.x;
  int lane = threadIdx.x & 63, w = threadIdx.x >> 6;
  int wm = w >> 2, wn = w & 3;
  int lg = lane >> 4, ll = lane & 15;
  const u16* Am = P + s * 65536;
  const u16* Bm = P + j * 65536;
  f32x4 acc[4][4];
  f32x4 z = {0.f, 0.f, 0.f, 0.f};
#pragma unroll
  for (int mi = 0; mi < 4; ++mi)
#pragma unroll
    for (int ni = 0; ni < 4; ++ni) acc[mi][ni] = z;
#pragma unroll
  for (int ks = 0; ks < 8; ++ks) {
    bf16x8 a[4], b[4];
    int kk = ks * 32 + lg * 8;
#pragma unroll
    for (int mi = 0; mi < 4; ++mi) {
      int row = mh * 128 + wm * 64 + mi * 16 + ll;
      a[mi] = *(const bf16x8*)(Am + row * 256 + kk);
    }
#pragma unroll
    for (int ni = 0; ni < 4; ++ni) {
      int col = wn * 64 + ni * 16 + ll;
#pragma unroll
      for (int e = 0; e < 8; ++e) b[ni][e] = (short)Bm[(kk + e) * 256 + col];
    }
#pragma unroll
    for (int mi = 0; mi < 4; ++mi)
#pragma unroll
      for (int ni = 0; ni < 4; ++ni) acc[mi][ni] = MFMA16(a[mi], b[ni], acc[mi][ni]);
  }
  u16* Pd = ws + OFF_P + (s + j) * 65536;
#pragma unroll
  for (int mi = 0; mi < 4; ++mi)
#pragma unroll
    for (int ni = 0; ni < 4; ++ni)
#pragma unroll
      for (int r = 0; r < 4; ++r) {
        int row = mh * 128 + wm * 64 + mi * 16 + lg * 4 + r;
        int col = wn * 64 + ni * 16 + ll;
        Pd[row * 256 + col] = f2bf(acc[mi][ni][r]);
      }
}

// ---------------- CrevT[n][s] = c_{63-s}[n] ----------------
__global__ void k_crevt(const float* __restrict__ B_w, u16* __restrict__ ws) {
  int s = blockIdx.x;
  int n = threadIdx.x;
  const u16* Pr = ws + OFF_P + (63 - s) * 65536 + n * 256;
  float acc = 0.f;
  for (int k = 0; k < 256; ++k) acc += bf2f(Pr[k]) * B_w[k];
  ws[OFF_CRT + n * 64 + s] = f2bf(acc);
}

// ---- A+B: KS gen + coalesced NT KS store + L1 (R17, proven) ----
__global__ __launch_bounds__(512) void k_ksl1(const u16* __restrict__ ws,
                                              const float* __restrict__ b0,
                                              u16* __restrict__ h1,
                                              float* __restrict__ out, int t0) {
  __shared__ __align__(16) u16 Xb[16896];             // [64][256] bf16 swz
  __shared__ __align__(16) unsigned char Hraw[33792]; // f32 bounce [32][260] / u16 Hb [64][264]
  __shared__ float pb0s[512];
  float* Hf = (float*)Hraw;
  u16* Hb = (u16*)Hraw;
  const int by = blockIdx.y;
  const int t  = t0 + by;
  const int R0 = blockIdx.x * 64;
  const int tid = threadIdx.x;
  const int lane = tid & 63, w = tid >> 6;
  const int lg = lane >> 4, ll = lane & 15;
  f32x4 z = {0.f, 0.f, 0.f, 0.f};

  pb0s[tid] = b0[tid];

  // ---- phase 1: KS rows R0..R0+63; wave w cols w*32..+31 ----
  f32x4 acc[4][2];
#pragma unroll
  for (int mi = 0; mi < 4; ++mi)
#pragma unroll
    for (int ni = 0; ni < 2; ++ni) acc[mi][ni] = z;
  {
    const u16* CrevT = ws + OFF_CRT;
    const u16* u8b = ws + OFF_U8 + (size_t)(t & 7) * U8_CPY + (t & ~7);
#pragma unroll
    for (int ksu = 0; ksu < 2; ++ksu) {
      bf16x8 au[4];
#pragma unroll
      for (int mi = 0; mi < 4; ++mi)
        au[mi] = *(const bf16x8*)(u8b + (R0 + mi * 16 + ll) * 584 + ksu * 32 + lg * 8);
#pragma unroll
      for (int ni = 0; ni < 2; ++ni) {
        int n = w * 32 + ni * 16 + ll;
        bf16x8 bfr = *(const bf16x8*)(CrevT + n * 64 + ksu * 32 + lg * 8);
#pragma unroll
        for (int mi = 0; mi < 4; ++mi) acc[mi][ni] = MFMA16(au[mi], bfr, acc[mi][ni]);
      }
    }
    if (t < 64) {
      const u16* Pt = ws + OFF_P + t * 65536;
      const u16* ks0b = ws + OFF_KS0;
#pragma unroll
      for (int ks = 0; ks < 8; ++ks) {
        bf16x8 a[4], b[2];
#pragma unroll
        for (int mi = 0; mi < 4; ++mi)
          a[mi] = *(const bf16x8*)(ks0b + (R0 + mi * 16 + ll) * 256 + ks * 32 + lg * 8);
#pragma unroll
        for (int ni = 0; ni < 2; ++ni)
          b[ni] = *(const bf16x8*)(Pt + (w * 32 + ni * 16 + ll) * 256 + ks * 32 + lg * 8);
#pragma unroll
        for (int mi = 0; mi < 4; ++mi)
#pragma unroll
          for (int ni = 0; ni < 2; ++ni) acc[mi][ni] = MFMA16(a[mi], b[ni], acc[mi][ni]);
      }
    }
  }

  // ---- build Xb (bf16 swz) straight from registers ----
#pragma unroll
  for (int mi = 0; mi < 4; ++mi)
#pragma unroll
    for (int ni = 0; ni < 2; ++ni)
#pragma unroll
      for (int r = 0; r < 4; ++r) {
        int rl = mi * 16 + lg * 4 + r;
        int col = w * 32 + ni * 16 + ll;
        int byt = ((rl << 9) + (col << 1)) ^ ((rl & 7) << 4);
        Xb[byt >> 1] = f2bf(acc[mi][ni][r]);
      }

  // ---- KS f32 store via bounce, 2 passes of 32 rows ----
#pragma unroll 1
  for (int p = 0; p < 2; ++p) {
#pragma unroll
    for (int mi2 = 0; mi2 < 2; ++mi2) {
      int mi = p * 2 + mi2;
#pragma unroll
      for (int ni = 0; ni < 2; ++ni)
#pragma unroll
        for (int r = 0; r < 4; ++r)
          Hf[(mi2 * 16 + lg * 4 + r) * 260 + w * 32 + ni * 16 + ll] = acc[mi][ni][r];
    }
    __syncthreads();
    float* ob = out + (size_t)t * 262144 + (size_t)(R0 + p * 32) * 256;
#pragma unroll
    for (int it = 0; it < 4; ++it) {
      int idx = it * 512 + tid;
      int row = idx >> 6, c4 = idx & 63;
      f32x4 v = *(const f32x4*)(Hf + row * 260 + c4 * 4);
      __builtin_nontemporal_store(v, (f32x4*)(ob + row * 256 + c4 * 4));
    }
    __syncthreads();
  }

  // ---- L1: H1 = tanh(X @ W0^T + b0); two 256-col halves; NT store to h1 ----
  const u16* W0b = ws + OFF_W0;
#pragma unroll 1
  for (int nh = 0; nh < 2; ++nh) {
    f32x4 acc2[4][2];
#pragma unroll
    for (int mi = 0; mi < 4; ++mi)
#pragma unroll
      for (int ni = 0; ni < 2; ++ni) acc2[mi][ni] = z;
#pragma unroll
    for (int ks = 0; ks < 8; ++ks) {
      bf16x8 b[2];
#pragma unroll
      for (int ni = 0; ni < 2; ++ni) {
        int n = nh * 256 + w * 32 + ni * 16 + ll;
        b[ni] = *(const bf16x8*)(W0b + n * 256 + ks * 32 + lg * 8);
      }
#pragma unroll
      for (int mi = 0; mi < 4; ++mi) {
        int rl = mi * 16 + ll;
        int byt = ((rl << 9) + ks * 64 + (lg << 4)) ^ ((rl & 7) << 4);
        bf16x8 a = *(const bf16x8*)(Xb + (byt >> 1));
#pragma unroll
        for (int ni = 0; ni < 2; ++ni) acc2[mi][ni] = MFMA16(a, b[ni], acc2[mi][ni]);
      }
    }
#pragma unroll
    for (int mi = 0; mi < 4; ++mi)
#pragma unroll
      for (int ni = 0; ni < 2; ++ni)
#pragma unroll
        for (int r = 0; r < 4; ++r) {
          int rl = mi * 16 + lg * 4 + r;
          int col = w * 32 + ni * 16 + ll;
          Hb[rl * 264 + col] = f2bf(fast_tanh(acc2[mi][ni][r] + pb0s[nh * 256 + col]));
        }
    __syncthreads();
    u16* hd = h1 + ((size_t)(by * 1024 + R0)) * 512 + nh * 256;
#pragma unroll
    for (int it = 0; it < 4; ++it) {
      int idx = it * 512 + tid;
      int row = idx >> 5, cq = idx & 31;
      bf16x8 v = *(const bf16x8*)(Hb + row * 264 + cq * 8);
      __builtin_nontemporal_store(v, (bf16x8*)(hd + row * 512 + cq * 8));
    }
    __syncthreads();
  }
}

// ---- C: OS = elu(LN(X + tanh(H1 @ W1^T + b1)) @ W2^T + b2) @ W3^T + b3 ----
// vs R17: both H1 halves staged to LDS BEFORE one barrier (concurrent HBM drain),
// then GEMM-0 + GEMM-1 back-to-back with no intermediate barrier. -2 barriers.
// (Lesson R18: loads can't be hidden ACROSS barriers; batch them into one drain.)
__global__ __launch_bounds__(512) void k_l23(const u16* __restrict__ ws,
                                             const float* __restrict__ outf,
                                             const float* __restrict__ b1,
                                             const float* __restrict__ lng,
                                             const float* __restrict__ lnb,
                                             const float* __restrict__ b2,
                                             const float* __restrict__ W3,
                                             const float* __restrict__ b3,
                                             const u16* __restrict__ h1,
                                             float* __restrict__ out, int t0) {
  __shared__ __align__(16) u16 Hs[16896];  // H1 half-0 stage swz / elu out [64][264]
  __shared__ __align__(16) u16 Rb[16896];  // H1 half-1 stage swz, then resid/LN [64][264]
  __shared__ float par[1796];
  __shared__ float osb[208];
  float* pb1 = par;          // 256
  float* pg  = par + 256;    // 256
  float* pbt = par + 512;    // 256
  float* pb2 = par + 768;    // 256
  float* pW3 = par + 1024;   // 768
  float* pb3 = par + 1792;   // 4
  const int by = blockIdx.y;
  const int t  = t0 + by;
  const int R0 = blockIdx.x * 64;
  const int tid = threadIdx.x;
  const int lane = tid & 63, w = tid >> 6;
  const int lg = lane >> 4, ll = lane & 15;
  f32x4 z = {0.f, 0.f, 0.f, 0.f};

  if (tid < 256) { pb1[tid] = b1[tid]; pg[tid] = lng[tid]; pbt[tid] = lnb[tid]; pb2[tid] = b2[tid]; }
  if (tid < 512) pW3[tid] = W3[tid];
  if (tid < 256) pW3[512 + tid] = W3[512 + tid];
  if (tid < 4) pb3[tid] = (tid < 3) ? b3[tid] : 0.f;

  const u16* W1b = ws + OFF_W1;
  const u16* h1b = h1 + ((size_t)(by * 1024 + R0)) * 512;

  // stage BOTH H1 halves (NT loads issued together -> one concurrent drain)
#pragma unroll
  for (int it = 0; it < 4; ++it) {
    int idx = it * 512 + tid;
    int row = idx >> 5, cq = idx & 31;
    bf16x8 a0 = __builtin_nontemporal_load((const bf16x8*)(h1b + row * 512 + cq * 8));
    bf16x8 a1 = __builtin_nontemporal_load((const bf16x8*)(h1b + row * 512 + 256 + cq * 8));
    int byt = ((row << 9) + (cq << 4)) ^ ((row & 7) << 4);
    *(bf16x8*)(Hs + (byt >> 1)) = a0;
    *(bf16x8*)((u16*)Rb + (byt >> 1)) = a1;
  }
  __syncthreads();

  f32x4 accL2[4][2];
#pragma unroll
  for (int mi = 0; mi < 4; ++mi)
#pragma unroll
    for (int ni = 0; ni < 2; ++ni) accL2[mi][ni] = z;

  // GEMM half 0 (Hs) + half 1 (Rb), back-to-back, no barrier between
#pragma unroll 1
  for (int kh = 0; kh < 2; ++kh) {
    const u16* src = kh ? (const u16*)Rb : (const u16*)Hs;
#pragma unroll
    for (int ks = 0; ks < 8; ++ks) {
      bf16x8 b[2];
#pragma unroll
      for (int ni = 0; ni < 2; ++ni) {
        int n = w * 32 + ni * 16 + ll;
        b[ni] = *(const bf16x8*)(W1b + n * 512 + kh * 256 + ks * 32 + lg * 8);
      }
#pragma unroll
      for (int mi = 0; mi < 4; ++mi) {
        int rl = mi * 16 + ll;
        int byt = ((rl << 9) + ks * 64 + (lg << 4)) ^ ((rl & 7) << 4);
        bf16x8 a = *(const bf16x8*)(src + (byt >> 1));
#pragma unroll
        for (int ni = 0; ni < 2; ++ni) accL2[mi][ni] = MFMA16(a, b[ni], accL2[mi][ni]);
      }
    }
  }
  __syncthreads();  // all GEMM reads done before resid overwrites Rb

  // residual: Rb = f2bf(X + tanh(accL2 + b1))
  {
    const float* xs = outf + (size_t)t * 262144 + (size_t)R0 * 256;
#pragma unroll
    for (int mi = 0; mi < 4; ++mi)
#pragma unroll
      for (int ni = 0; ni < 2; ++ni)
#pragma unroll
        for (int r = 0; r < 4; ++r) {
          int rl = mi * 16 + lg * 4 + r;
          int col = w * 32 + ni * 16 + ll;
          float xv = __builtin_nontemporal_load(xs + rl * 256 + col);
          float v = xv + fast_tanh(accL2[mi][ni][r] + pb1[col]);
          Rb[rl * 264 + col] = f2bf(v);
        }
  }
  __syncthreads();

  // LayerNorm per row in place; 8 lanes/row
  {
    int row = tid >> 3, jq = tid & 7;
    u16* hr = Rb + row * 264 + jq * 32;
    bf16x8 chv[4];
#pragma unroll
    for (int q = 0; q < 4; ++q) chv[q] = *(const bf16x8*)(hr + q * 8);
    float s = 0.f, ss = 0.f;
#pragma unroll
    for (int q = 0; q < 4; ++q)
#pragma unroll
      for (int e = 0; e < 8; ++e) { float v = bf2f((u16)chv[q][e]); s += v; ss += v * v; }
    s += __shfl_xor(s, 1);  s += __shfl_xor(s, 2);  s += __shfl_xor(s, 4);
    ss += __shfl_xor(ss, 1); ss += __shfl_xor(ss, 2); ss += __shfl_xor(ss, 4);
    float mu = s * 0.00390625f;
    float var = ss * 0.00390625f - mu * mu;
    float rstd = rsqrtf(var + 1e-5f);
#pragma unroll
    for (int q = 0; q < 4; ++q) {
      bf16x8 o;
#pragma unroll
      for (int e = 0; e < 8; ++e) {
        int col = jq * 32 + q * 8 + e;
        float v = (bf2f((u16)chv[q][e]) - mu) * rstd * pg[col] + pbt[col];
        o[e] = (short)f2bf(v);
      }
      *(bf16x8*)(hr + q * 8) = o;
    }
  }
  __syncthreads();

  // L3: elu(s2n @ W2^T + b2) -> Hs (reused) [64][264]
  {
    const u16* W2b = ws + OFF_W2;
    f32x4 a3[4][2];
#pragma unroll
    for (int mi = 0; mi < 4; ++mi)
#pragma unroll
      for (int ni = 0; ni < 2; ++ni) a3[mi][ni] = z;
#pragma unroll
    for (int ks = 0; ks < 8; ++ks) {
      bf16x8 b[2];
#pragma unroll
      for (int ni = 0; ni < 2; ++ni) {
        int n = w * 32 + ni * 16 + ll;
        b[ni] = *(const bf16x8*)(W2b + n * 256 + ks * 32 + lg * 8);
      }
#pragma unroll
      for (int mi = 0; mi < 4; ++mi) {
        int rl = mi * 16 + ll;
        bf16x8 a = *(const bf16x8*)(Rb + rl * 264 + ks * 32 + lg * 8);
#pragma unroll
        for (int ni = 0; ni < 2; ++ni) a3[mi][ni] = MFMA16(a, b[ni], a3[mi][ni]);
      }
    }
#pragma unroll
    for (int mi = 0; mi < 4; ++mi)
#pragma unroll
      for (int ni = 0; ni < 2; ++ni)
#pragma unroll
        for (int r = 0; r < 4; ++r) {
          int rl = mi * 16 + lg * 4 + r;
          int col = w * 32 + ni * 16 + ll;
          float v = a3[mi][ni][r] + pb2[col];
          v = v > 0.f ? v : (__expf(v) - 1.f);
          Hs[rl * 264 + col] = f2bf(v);
        }
  }
  __syncthreads();

  // OS reduce into LDS, then coalesced store
  {
    int row = tid >> 3, jq = tid & 7;
    const u16* xr = Hs + row * 264 + jq * 32;
    float d0 = 0.f, d1 = 0.f, d2 = 0.f;
#pragma unroll
    for (int q = 0; q < 4; ++q) {
      bf16x8 c = *(const bf16x8*)(xr + q * 8);
#pragma unroll
      for (int e = 0; e < 8; ++e) {
        float v = bf2f((u16)c[e]);
        int col = jq * 32 + q * 8 + e;
        d0 += v * pW3[col]; d1 += v * pW3[256 + col]; d2 += v * pW3[512 + col];
      }
    }
    d0 += __shfl_xor(d0, 1); d0 += __shfl_xor(d0, 2); d0 += __shfl_xor(d0, 4);
    d1 += __shfl_xor(d1, 1); d1 += __shfl_xor(d1, 2); d1 += __shfl_xor(d1, 4);
    d2 += __shfl_xor(d2, 1); d2 += __shfl_xor(d2, 2); d2 += __shfl_xor(d2, 4);
    if (jq == 0) {
      osb[row * 3]     = d0 + pb3[0];
      osb[row * 3 + 1] = d1 + pb3[1];
      osb[row * 3 + 2] = d2 + pb3[2];
    }
  }
  __syncthreads();
  if (tid < 48) {
    f32x4 v = *(const f32x4*)(osb + tid * 4);
    __builtin_nontemporal_store(v, (f32x4*)(out + OS_OFF + (size_t)t * 3072 + (size_t)R0 * 3 + tid * 4));
  }
}

extern "C" void kernel_launch(void* const* d_in, const int* in_sizes, int n_in,
                              void* d_out, int out_size, void* d_ws, size_t ws_size,
                              hipStream_t stream) {
  const float* KS_ALL  = (const float*)d_in[0];
  const float* next_vf = (const float*)d_in[1];
  const float* A_w     = (const float*)d_in[2];
  const float* B_w     = (const float*)d_in[3];
  const float* W0      = (const float*)d_in[4];
  const float* b0      = (const float*)d_in[5];
  const float* W1      = (const float*)d_in[6];
  const float* b1      = (const float*)d_in[7];
  const float* lng     = (const float*)d_in[8];
  const float* lnb     = (const float*)d_in[9];
  const float* W2      = (const float*)d_in[10];
  const float* b2      = (const float*)d_in[11];
  const float* W3      = (const float*)d_in[12];
  const float* b3      = (const float*)d_in[13];
  u16* ws = (u16*)d_ws;
  float* out = (float*)d_out;

  k_prep<<<21248, 256, 0, stream>>>(KS_ALL, next_vf, A_w, W0, W1, W2, ws);
  for (int s = 1; s <= 32; s <<= 1)
    k_pow<<<dim3(2, s), 512, 0, stream>>>(ws, s);
  k_crevt<<<64, 256, 0, stream>>>(B_w, ws);

  u16* h1 = ws + OFF_H1;
  const int t0s[4] = {0, 129, 257, 385};
  const int nts[4] = {129, 128, 128, 128};
  for (int c = 0; c < 4; ++c) {
    k_ksl1<<<dim3(16, nts[c]), 512, 0, stream>>>(ws, b0, h1, out, t0s[c]);
    k_l23<<<dim3(16, nts[c]), 512, 0, stream>>>(ws, out, b1, lng, lnb, b2, W3, b3, h1, out, t0s[c]);
  }
}

// Round 20
// 1368.856 us; speedup vs baseline: 1.1416x; 1.0002x over previous
//
#include <hip/hip_runtime.h>

typedef unsigned short u16;
typedef __attribute__((ext_vector_type(8))) short bf16x8;
typedef __attribute__((ext_vector_type(4))) short bf16x4;
typedef __attribute__((ext_vector_type(4))) float f32x4;

#define MFMA16(a, b, c) __builtin_amdgcn_mfma_f32_16x16x32_bf16((a), (b), (c), 0, 0, 0)

// workspace layout (u16 element offsets)
#define OFF_U8   0           // 8 shifted u_pad copies: [8][1024][584]
#define U8_CPY   598016      // 1024*584
#define OFF_KS0  4784128
#define OFF_W0   5046272
#define OFF_W1   5177344
#define OFF_W2   5308416
#define OFF_CRT  5373952
#define OFF_P    5390336     // 65 x 65536 (A^t, bf16)
#define OFF_H1   9650176     // chunk H1: 129*1024*512 u16
#define OS_OFF   134479872   // 513*1024*256

__device__ __forceinline__ u16 f2bf(float f) {
  union { float f; unsigned int i; } v; v.f = f;
  return (u16)((v.i + 0x7fffu + ((v.i >> 16) & 1u)) >> 16);
}
__device__ __forceinline__ float bf2f(u16 u) {
  union { unsigned int i; float f; } v; v.i = ((unsigned int)u) << 16;
  return v.f;
}
__device__ __forceinline__ float fast_tanh(float x) {
  float e = __expf(2.0f * x);
  return 1.0f - __fdividef(2.0f, e + 1.0f);
}

// ---------------- prep: u8 shifted copies + bf16 conversions + P0/P1 ----------------
__global__ void k_prep(const float* __restrict__ KS_ALL, const float* __restrict__ next_vf,
                       const float* __restrict__ A_w, const float* __restrict__ W0,
                       const float* __restrict__ W1, const float* __restrict__ W2,
                       u16* __restrict__ ws) {
  int idx = blockIdx.x * 256 + threadIdx.x;
  if (idx < 4784128) {  // u8[p][b][c] = u_pad[b][c+p]
    int p = idx / U8_CPY;
    int rem = idx - p * U8_CPY;
    int b = rem / 584;
    int c = rem - b * 584;
    int col = c + p;
    ws[OFF_U8 + idx] = (col >= 64 && col < 576) ? f2bf(next_vf[b * 512 + col - 64]) : (u16)0;
    return;
  }
  idx -= 4784128;
  if (idx < 262144) { ws[OFF_KS0 + idx] = f2bf(KS_ALL[idx]); return; }
  idx -= 262144;
  if (idx < 131072) { ws[OFF_W0 + idx] = f2bf(W0[idx]); return; }
  idx -= 131072;
  if (idx < 131072) { ws[OFF_W1 + idx] = f2bf(W1[idx]); return; }
  idx -= 131072;
  if (idx < 65536)  { ws[OFF_W2 + idx] = f2bf(W2[idx]); return; }
  idx -= 65536;
  if (idx < 65536) { // P0 = I, P1 = A
    int r = idx >> 8, c = idx & 255;
    ws[OFF_P + idx] = (r == c) ? (u16)0x3F80 : (u16)0;
    ws[OFF_P + 65536 + idx] = f2bf(A_w[idx]);
  }
}

// ---------------- power doubling ----------------
__global__ __launch_bounds__(512) void k_pow(u16* __restrict__ ws, int s) {
  const u16* P = ws + OFF_P;
  int j = blockIdx.y + 1;
  int mh = blockIdx.x;
  int lane = threadIdx.x & 63, w = threadIdx.x >> 6;
  int wm = w >> 2, wn = w & 3;
  int lg = lane >> 4, ll = lane & 15;
  const u16* Am = P + s * 65536;
  const u16* Bm = P + j * 65536;
  f32x4 acc[4][4];
  f32x4 z = {0.f, 0.f, 0.f, 0.f};
#pragma unroll
  for (int mi = 0; mi < 4; ++mi)
#pragma unroll
    for (int ni = 0; ni < 4; ++ni) acc[mi][ni] = z;
#pragma unroll
  for (int ks = 0; ks < 8; ++ks) {
    bf16x8 a[4], b[4];
    int kk = ks * 32 + lg * 8;
#pragma unroll
    for (int mi = 0; mi < 4; ++mi) {
      int row = mh * 128 + wm * 64 + mi * 16 + ll;
      a[mi] = *(const bf16x8*)(Am + row * 256 + kk);
    }
#pragma unroll
    for (int ni = 0; ni < 4; ++ni) {
      int col = wn * 64 + ni * 16 + ll;
#pragma unroll
      for (int e = 0; e < 8; ++e) b[ni][e] = (short)Bm[(kk + e) * 256 + col];
    }
#pragma unroll
    for (int mi = 0; mi < 4; ++mi)
#pragma unroll
      for (int ni = 0; ni < 4; ++ni) acc[mi][ni] = MFMA16(a[mi], b[ni], acc[mi][ni]);
  }
  u16* Pd = ws + OFF_P + (s + j) * 65536;
#pragma unroll
  for (int mi = 0; mi < 4; ++mi)
#pragma unroll
    for (int ni = 0; ni < 4; ++ni)
#pragma unroll
      for (int r = 0; r < 4; ++r) {
        int row = mh * 128 + wm * 64 + mi * 16 + lg * 4 + r;
        int col = wn * 64 + ni * 16 + ll;
        Pd[row * 256 + col] = f2bf(acc[mi][ni][r]);
      }
}

// ---------------- CrevT[n][s] = c_{63-s}[n] ----------------
__global__ void k_crevt(const float* __restrict__ B_w, u16* __restrict__ ws) {
  int s = blockIdx.x;
  int n = threadIdx.x;
  const u16* Pr = ws + OFF_P + (63 - s) * 65536 + n * 256;
  float acc = 0.f;
  for (int k = 0; k < 256; ++k) acc += bf2f(Pr[k]) * B_w[k];
  ws[OFF_CRT + n * 64 + s] = f2bf(acc);
}

// ---- A+B: KS gen + coalesced NT KS store + L1 (R17/R19, proven) ----
__global__ __launch_bounds__(512) void k_ksl1(const u16* __restrict__ ws,
                                              const float* __restrict__ b0,
                                              u16* __restrict__ h1,
                                              float* __restrict__ out, int t0) {
  __shared__ __align__(16) u16 Xb[16896];             // [64][256] bf16 swz
  __shared__ __align__(16) unsigned char Hraw[33792]; // f32 bounce [32][260] / u16 Hb [64][264]
  __shared__ float pb0s[512];
  float* Hf = (float*)Hraw;
  u16* Hb = (u16*)Hraw;
  const int by = blockIdx.y;
  const int t  = t0 + by;
  const int R0 = blockIdx.x * 64;
  const int tid = threadIdx.x;
  const int lane = tid & 63, w = tid >> 6;
  const int lg = lane >> 4, ll = lane & 15;
  f32x4 z = {0.f, 0.f, 0.f, 0.f};

  pb0s[tid] = b0[tid];

  // ---- phase 1: KS rows R0..R0+63; wave w cols w*32..+31 ----
  f32x4 acc[4][2];
#pragma unroll
  for (int mi = 0; mi < 4; ++mi)
#pragma unroll
    for (int ni = 0; ni < 2; ++ni) acc[mi][ni] = z;
  {
    const u16* CrevT = ws + OFF_CRT;
    const u16* u8b = ws + OFF_U8 + (size_t)(t & 7) * U8_CPY + (t & ~7);
#pragma unroll
    for (int ksu = 0; ksu < 2; ++ksu) {
      bf16x8 au[4];
#pragma unroll
      for (int mi = 0; mi < 4; ++mi)
        au[mi] = *(const bf16x8*)(u8b + (R0 + mi * 16 + ll) * 584 + ksu * 32 + lg * 8);
#pragma unroll
      for (int ni = 0; ni < 2; ++ni) {
        int n = w * 32 + ni * 16 + ll;
        bf16x8 bfr = *(const bf16x8*)(CrevT + n * 64 + ksu * 32 + lg * 8);
#pragma unroll
        for (int mi = 0; mi < 4; ++mi) acc[mi][ni] = MFMA16(au[mi], bfr, acc[mi][ni]);
      }
    }
    if (t < 64) {
      const u16* Pt = ws + OFF_P + t * 65536;
      const u16* ks0b = ws + OFF_KS0;
#pragma unroll
      for (int ks = 0; ks < 8; ++ks) {
        bf16x8 a[4], b[2];
#pragma unroll
        for (int mi = 0; mi < 4; ++mi)
          a[mi] = *(const bf16x8*)(ks0b + (R0 + mi * 16 + ll) * 256 + ks * 32 + lg * 8);
#pragma unroll
        for (int ni = 0; ni < 2; ++ni)
          b[ni] = *(const bf16x8*)(Pt + (w * 32 + ni * 16 + ll) * 256 + ks * 32 + lg * 8);
#pragma unroll
        for (int mi = 0; mi < 4; ++mi)
#pragma unroll
          for (int ni = 0; ni < 2; ++ni) acc[mi][ni] = MFMA16(a[mi], b[ni], acc[mi][ni]);
      }
    }
  }

  // ---- build Xb (bf16 swz) straight from registers ----
#pragma unroll
  for (int mi = 0; mi < 4; ++mi)
#pragma unroll
    for (int ni = 0; ni < 2; ++ni)
#pragma unroll
      for (int r = 0; r < 4; ++r) {
        int rl = mi * 16 + lg * 4 + r;
        int col = w * 32 + ni * 16 + ll;
        int byt = ((rl << 9) + (col << 1)) ^ ((rl & 7) << 4);
        Xb[byt >> 1] = f2bf(acc[mi][ni][r]);
      }

  // ---- KS f32 store via bounce, 2 passes of 32 rows ----
#pragma unroll 1
  for (int p = 0; p < 2; ++p) {
#pragma unroll
    for (int mi2 = 0; mi2 < 2; ++mi2) {
      int mi = p * 2 + mi2;
#pragma unroll
      for (int ni = 0; ni < 2; ++ni)
#pragma unroll
        for (int r = 0; r < 4; ++r)
          Hf[(mi2 * 16 + lg * 4 + r) * 260 + w * 32 + ni * 16 + ll] = acc[mi][ni][r];
    }
    __syncthreads();
    float* ob = out + (size_t)t * 262144 + (size_t)(R0 + p * 32) * 256;
#pragma unroll
    for (int it = 0; it < 4; ++it) {
      int idx = it * 512 + tid;
      int row = idx >> 6, c4 = idx & 63;
      f32x4 v = *(const f32x4*)(Hf + row * 260 + c4 * 4);
      __builtin_nontemporal_store(v, (f32x4*)(ob + row * 256 + c4 * 4));
    }
    __syncthreads();
  }

  // ---- L1: H1 = tanh(X @ W0^T + b0); two 256-col halves; NT store to h1 ----
  const u16* W0b = ws + OFF_W0;
#pragma unroll 1
  for (int nh = 0; nh < 2; ++nh) {
    f32x4 acc2[4][2];
#pragma unroll
    for (int mi = 0; mi < 4; ++mi)
#pragma unroll
      for (int ni = 0; ni < 2; ++ni) acc2[mi][ni] = z;
#pragma unroll
    for (int ks = 0; ks < 8; ++ks) {
      bf16x8 b[2];
#pragma unroll
      for (int ni = 0; ni < 2; ++ni) {
        int n = nh * 256 + w * 32 + ni * 16 + ll;
        b[ni] = *(const bf16x8*)(W0b + n * 256 + ks * 32 + lg * 8);
      }
#pragma unroll
      for (int mi = 0; mi < 4; ++mi) {
        int rl = mi * 16 + ll;
        int byt = ((rl << 9) + ks * 64 + (lg << 4)) ^ ((rl & 7) << 4);
        bf16x8 a = *(const bf16x8*)(Xb + (byt >> 1));
#pragma unroll
        for (int ni = 0; ni < 2; ++ni) acc2[mi][ni] = MFMA16(a, b[ni], acc2[mi][ni]);
      }
    }
#pragma unroll
    for (int mi = 0; mi < 4; ++mi)
#pragma unroll
      for (int ni = 0; ni < 2; ++ni)
#pragma unroll
        for (int r = 0; r < 4; ++r) {
          int rl = mi * 16 + lg * 4 + r;
          int col = w * 32 + ni * 16 + ll;
          Hb[rl * 264 + col] = f2bf(fast_tanh(acc2[mi][ni][r] + pb0s[nh * 256 + col]));
        }
    __syncthreads();
    u16* hd = h1 + ((size_t)(by * 1024 + R0)) * 512 + nh * 256;
#pragma unroll
    for (int it = 0; it < 4; ++it) {
      int idx = it * 512 + tid;
      int row = idx >> 5, cq = idx & 31;
      bf16x8 v = *(const bf16x8*)(Hb + row * 264 + cq * 8);
      __builtin_nontemporal_store(v, (bf16x8*)(hd + row * 512 + cq * 8));
    }
    __syncthreads();
  }
}

// ---- C: BM=128, 1024 thr / 16 waves, pure N-split (wave w owns 16 cols).
// Halves block count -> ~4 serial block-chains/CU instead of 8; per-phase
// latency amortized over 2x data. LDS: Sb 67.6KB + Rb 67.6KB + par ~8.8KB = 144KB.
__global__ __launch_bounds__(1024) void k_l23(const u16* __restrict__ ws,
                                              const float* __restrict__ outf,
                                              const float* __restrict__ b1,
                                              const float* __restrict__ lng,
                                              const float* __restrict__ lnb,
                                              const float* __restrict__ b2,
                                              const float* __restrict__ W3,
                                              const float* __restrict__ b3,
                                              const u16* __restrict__ h1,
                                              float* __restrict__ out, int t0) {
  __shared__ __align__(16) u16 Sb[33792];  // H1-half stage [128][256] swz / elu [128][264]
  __shared__ __align__(16) u16 Rb[33792];  // resid/LN [128][264]
  __shared__ float par[1796];
  __shared__ float osb[384];
  float* pb1 = par;          // 256
  float* pg  = par + 256;    // 256
  float* pbt = par + 512;    // 256
  float* pb2 = par + 768;    // 256
  float* pW3 = par + 1024;   // 768
  float* pb3 = par + 1792;   // 4
  const int by = blockIdx.y;
  const int t  = t0 + by;
  const int R0 = blockIdx.x * 128;
  const int tid = threadIdx.x;
  const int lane = tid & 63, w = tid >> 6;   // w = 0..15
  const int lg = lane >> 4, ll = lane & 15;
  const int colW = w * 16 + ll;              // wave's output col, 0..255
  f32x4 z = {0.f, 0.f, 0.f, 0.f};

  if (tid < 256) { pb1[tid] = b1[tid]; pg[tid] = lng[tid]; pbt[tid] = lnb[tid]; pb2[tid] = b2[tid]; }
  if (tid < 768) pW3[tid] = W3[tid];
  if (tid < 4) pb3[tid] = (tid < 3) ? b3[tid] : 0.f;

  const u16* W1b = ws + OFF_W1;
  const u16* h1b = h1 + ((size_t)(by * 1024 + R0)) * 512;

  f32x4 accL2[8];
#pragma unroll
  for (int mi = 0; mi < 8; ++mi) accL2[mi] = z;

  // two K-halves: stage [128][256] swz into Sb, then GEMM
#pragma unroll 1
  for (int kh = 0; kh < 2; ++kh) {
#pragma unroll
    for (int it = 0; it < 4; ++it) {
      int idx = it * 1024 + tid;
      int row = idx >> 5, cq = idx & 31;
      bf16x8 v = __builtin_nontemporal_load((const bf16x8*)(h1b + row * 512 + kh * 256 + cq * 8));
      int byt = ((row << 9) + (cq << 4)) ^ ((row & 7) << 4);
      *(bf16x8*)(Sb + (byt >> 1)) = v;
    }
    __syncthreads();
#pragma unroll
    for (int ks = 0; ks < 8; ++ks) {
      bf16x8 b = *(const bf16x8*)(W1b + colW * 512 + kh * 256 + ks * 32 + lg * 8);
#pragma unroll
      for (int mi = 0; mi < 8; ++mi) {
        int rl = mi * 16 + ll;
        int byt = ((rl << 9) + ks * 64 + (lg << 4)) ^ ((rl & 7) << 4);
        bf16x8 a = *(const bf16x8*)(Sb + (byt >> 1));
        accL2[mi] = MFMA16(a, b, accL2[mi]);
      }
    }
    __syncthreads();
  }

  // residual: Rb = f2bf(X + tanh(accL2 + b1))
  {
    const float* xs = outf + (size_t)t * 262144 + (size_t)R0 * 256;
#pragma unroll
    for (int mi = 0; mi < 8; ++mi)
#pragma unroll
      for (int r = 0; r < 4; ++r) {
        int rl = mi * 16 + lg * 4 + r;
        float xv = __builtin_nontemporal_load(xs + rl * 256 + colW);
        float v = xv + fast_tanh(accL2[mi][r] + pb1[colW]);
        Rb[rl * 264 + colW] = f2bf(v);
      }
  }
  __syncthreads();

  // LayerNorm per row in place; 8 lanes/row over 128 rows (1024 thr)
  {
    int row = tid >> 3, jq = tid & 7;
    u16* hr = Rb + row * 264 + jq * 32;
    bf16x8 chv[4];
#pragma unroll
    for (int q = 0; q < 4; ++q) chv[q] = *(const bf16x8*)(hr + q * 8);
    float s = 0.f, ss = 0.f;
#pragma unroll
    for (int q = 0; q < 4; ++q)
#pragma unroll
      for (int e = 0; e < 8; ++e) { float v = bf2f((u16)chv[q][e]); s += v; ss += v * v; }
    s += __shfl_xor(s, 1);  s += __shfl_xor(s, 2);  s += __shfl_xor(s, 4);
    ss += __shfl_xor(ss, 1); ss += __shfl_xor(ss, 2); ss += __shfl_xor(ss, 4);
    float mu = s * 0.00390625f;
    float var = ss * 0.00390625f - mu * mu;
    float rstd = rsqrtf(var + 1e-5f);
#pragma unroll
    for (int q = 0; q < 4; ++q) {
      bf16x8 o;
#pragma unroll
      for (int e = 0; e < 8; ++e) {
        int col = jq * 32 + q * 8 + e;
        float v = (bf2f((u16)chv[q][e]) - mu) * rstd * pg[col] + pbt[col];
        o[e] = (short)f2bf(v);
      }
      *(bf16x8*)(hr + q * 8) = o;
    }
  }
  __syncthreads();

  // L3: elu(s2n @ W2^T + b2) -> Sb [128][264]
  {
    const u16* W2b = ws + OFF_W2;
    f32x4 a3[8];
#pragma unroll
    for (int mi = 0; mi < 8; ++mi) a3[mi] = z;
#pragma unroll
    for (int ks = 0; ks < 8; ++ks) {
      bf16x8 b = *(const bf16x8*)(W2b + colW * 256 + ks * 32 + lg * 8);
#pragma unroll
      for (int mi = 0; mi < 8; ++mi) {
        int rl = mi * 16 + ll;
        bf16x8 a = *(const bf16x8*)(Rb + rl * 264 + ks * 32 + lg * 8);
        a3[mi] = MFMA16(a, b, a3[mi]);
      }
    }
#pragma unroll
    for (int mi = 0; mi < 8; ++mi)
#pragma unroll
      for (int r = 0; r < 4; ++r) {
        int rl = mi * 16 + lg * 4 + r;
        float v = a3[mi][r] + pb2[colW];
        v = v > 0.f ? v : (__expf(v) - 1.f);
        Sb[rl * 264 + colW] = f2bf(v);
      }
  }
  __syncthreads();

  // OS reduce into LDS, then coalesced store; 8 lanes/row over 128 rows
  {
    int row = tid >> 3, jq = tid & 7;
    const u16* xr = Sb + row * 264 + jq * 32;
    float d0 = 0.f, d1 = 0.f, d2 = 0.f;
#pragma unroll
    for (int q = 0; q < 4; ++q) {
      bf16x8 c = *(const bf16x8*)(xr + q * 8);
#pragma unroll
      for (int e = 0; e < 8; ++e) {
        float v = bf2f((u16)c[e]);
        int col = jq * 32 + q * 8 + e;
        d0 += v * pW3[col]; d1 += v * pW3[256 + col]; d2 += v * pW3[512 + col];
      }
    }
    d0 += __shfl_xor(d0, 1); d0 += __shfl_xor(d0, 2); d0 += __shfl_xor(d0, 4);
    d1 += __shfl_xor(d1, 1); d1 += __shfl_xor(d1, 2); d1 += __shfl_xor(d1, 4);
    d2 += __shfl_xor(d2, 1); d2 += __shfl_xor(d2, 2); d2 += __shfl_xor(d2, 4);
    if (jq == 0) {
      osb[row * 3]     = d0 + pb3[0];
      osb[row * 3 + 1] = d1 + pb3[1];
      osb[row * 3 + 2] = d2 + pb3[2];
    }
  }
  __syncthreads();
  if (tid < 96) {
    f32x4 v = *(const f32x4*)(osb + tid * 4);
    __builtin_nontemporal_store(v, (f32x4*)(out + OS_OFF + (size_t)t * 3072 + (size_t)R0 * 3 + tid * 4));
  }
}

extern "C" void kernel_launch(void* const* d_in, const int* in_sizes, int n_in,
                              void* d_out, int out_size, void* d_ws, size_t ws_size,
                              hipStream_t stream) {
  const float* KS_ALL  = (const float*)d_in[0];
  const float* next_vf = (const float*)d_in[1];
  const float* A_w     = (const float*)d_in[2];
  const float* B_w     = (const float*)d_in[3];
  const float* W0      = (const float*)d_in[4];
  const float* b0      = (const float*)d_in[5];
  const float* W1      = (const float*)d_in[6];
  const float* b1      = (const float*)d_in[7];
  const float* lng     = (const float*)d_in[8];
  const float* lnb     = (const float*)d_in[9];
  const float* W2      = (const float*)d_in[10];
  const float* b2      = (const float*)d_in[11];
  const float* W3      = (const float*)d_in[12];
  const float* b3      = (const float*)d_in[13];
  u16* ws = (u16*)d_ws;
  float* out = (float*)d_out;

  k_prep<<<21248, 256, 0, stream>>>(KS_ALL, next_vf, A_w, W0, W1, W2, ws);
  for (int s = 1; s <= 32; s <<= 1)
    k_pow<<<dim3(2, s), 512, 0, stream>>>(ws, s);
  k_crevt<<<64, 256, 0, stream>>>(B_w, ws);

  u16* h1 = ws + OFF_H1;
  const int t0s[4] = {0, 129, 257, 385};
  const int nts[4] = {129, 128, 128, 128};
  for (int c = 0; c < 4; ++c) {
    k_ksl1<<<dim3(16, nts[c]), 512, 0, stream>>>(ws, b0, h1, out, t0s[c]);
    k_l23<<<dim3(8, nts[c]), 1024, 0, stream>>>(ws, out, b1, lng, lnb, b2, W3, b3, h1, out, t0s[c]);
  }
}